// Round 7
// baseline (293.583 us; speedup 1.0000x reference)
//
#include <hip/hip_runtime.h>
#include <hip/hip_bf16.h>

#define HEADS 4
#define OUT_C 64
#define CH 256           // HEADS*OUT_C == IN_C == 256
#define NEG_SLOPE 0.2f

typedef short short8 __attribute__((ext_vector_type(8)));
typedef float f32x4 __attribute__((ext_vector_type(4)));

__device__ inline float bflo(unsigned int u) {
    return __uint_as_float(u << 16);
}
__device__ inline float bfhi(unsigned int u) {
    return __uint_as_float(u & 0xFFFF0000u);
}
__device__ inline unsigned short f2bf(float f) {
    __hip_bfloat16 b = __float2bfloat16(f);   // RNE
    return *reinterpret_cast<unsigned short*>(&b);
}

#define GLOAD_LDS16(g, l)                                                   \
    __builtin_amdgcn_global_load_lds(                                       \
        (const __attribute__((address_space(1))) void*)(g),                 \
        (__attribute__((address_space(3))) void*)(l), 16, 0, 0)

// ---------------------------------------------------------------------------
// K1: count in-degree per dst (cursor pre-zeroed by hipMemsetAsync).
// ---------------------------------------------------------------------------
__global__ __launch_bounds__(256) void count_kernel(const int4* __restrict__ dst4,
                                                    int* __restrict__ cursor,
                                                    int N, int E4) {
    int i = blockIdx.x * 256 + threadIdx.x;
    if (i < E4) {
        int4 d = dst4[i];
        if ((unsigned)d.x < (unsigned)N) atomicAdd(&cursor[d.x], 1);
        if ((unsigned)d.y < (unsigned)N) atomicAdd(&cursor[d.y], 1);
        if ((unsigned)d.z < (unsigned)N) atomicAdd(&cursor[d.z], 1);
        if ((unsigned)d.w < (unsigned)N) atomicAdd(&cursor[d.w], 1);
    }
}

// ---------------------------------------------------------------------------
// K2a/b/c: parallel 3-phase exclusive scan of (deg+1) -> rowptr (+cursor copy)
// ---------------------------------------------------------------------------
__global__ __launch_bounds__(256) void scan_p1(const int* __restrict__ deg,
                                               int* __restrict__ blocksum, int N) {
    __shared__ int ws[4];
    int t = threadIdx.x;
    int i = blockIdx.x * 256 + t;
    int v = (i < N) ? deg[i] + 1 : 0;
    #pragma unroll
    for (int o = 32; o > 0; o >>= 1) v += __shfl_xor(v, o, 64);
    if ((t & 63) == 0) ws[t >> 6] = v;
    __syncthreads();
    if (t == 0) blocksum[blockIdx.x] = ws[0] + ws[1] + ws[2] + ws[3];
}

__global__ __launch_bounds__(256) void scan_p2(const int* __restrict__ blocksum,
                                               int* __restrict__ blockoff,
                                               int* __restrict__ rowptrN, int SB) {
    __shared__ int ws[4];
    int t = threadIdx.x;
    int lane = t & 63, w = t >> 6;
    int v = (t < SB) ? blocksum[t] : 0;
    int incl = v;
    #pragma unroll
    for (int o = 1; o < 64; o <<= 1) {
        int x = __shfl_up(incl, o, 64);
        if (lane >= o) incl += x;
    }
    if (lane == 63) ws[w] = incl;
    __syncthreads();
    int off = 0;
    #pragma unroll
    for (int j = 0; j < 4; ++j) if (j < w) off += ws[j];
    int excl = off + incl - v;
    if (t < SB) blockoff[t] = excl;
    if (t == 255) rowptrN[0] = excl + v;   // grand total (SB<=256)
}

__global__ __launch_bounds__(256) void scan_p3(const int* __restrict__ deg,
                                               const int* __restrict__ blockoff,
                                               int* __restrict__ rowptr,
                                               int* __restrict__ cursor, int N) {
    __shared__ int ws[4];
    int t = threadIdx.x;
    int i = blockIdx.x * 256 + t;
    int lane = t & 63, w = t >> 6;
    int v = (i < N) ? deg[i] + 1 : 0;
    int incl = v;
    #pragma unroll
    for (int o = 1; o < 64; o <<= 1) {
        int x = __shfl_up(incl, o, 64);
        if (lane >= o) incl += x;
    }
    if (lane == 63) ws[w] = incl;
    __syncthreads();
    int off = 0;
    #pragma unroll
    for (int j = 0; j < 4; ++j) if (j < w) off += ws[j];
    int excl = blockoff[blockIdx.x] + off + incl - v;
    if (i < N) { rowptr[i] = excl; cursor[i] = excl; }
}

// ---------------------------------------------------------------------------
// K3: scatter edges (int4 = 4 edges/thread) and self loops into CSR src lists
// ---------------------------------------------------------------------------
__global__ __launch_bounds__(256) void scatter_kernel(const int* __restrict__ ei,
                                                      int* __restrict__ cursor,
                                                      int* __restrict__ srclist,
                                                      int N, int E) {
    int i = blockIdx.x * 256 + threadIdx.x;
    int E4 = E >> 2;
    if (i < E4) {
        int4 s4 = ((const int4*)ei)[i];
        int4 d4 = ((const int4*)(ei + E))[i];
        if ((unsigned)s4.x < (unsigned)N && (unsigned)d4.x < (unsigned)N)
            srclist[atomicAdd(&cursor[d4.x], 1)] = s4.x;
        if ((unsigned)s4.y < (unsigned)N && (unsigned)d4.y < (unsigned)N)
            srclist[atomicAdd(&cursor[d4.y], 1)] = s4.y;
        if ((unsigned)s4.z < (unsigned)N && (unsigned)d4.z < (unsigned)N)
            srclist[atomicAdd(&cursor[d4.z], 1)] = s4.z;
        if ((unsigned)s4.w < (unsigned)N && (unsigned)d4.w < (unsigned)N)
            srclist[atomicAdd(&cursor[d4.w], 1)] = s4.w;
    } else if (i < E4 + N) {
        int n = i - E4;
        srclist[atomicAdd(&cursor[n], 1)] = n;
    }
}

// ---------------------------------------------------------------------------
// K4a: W transpose+convert -> wt[n][k] bf16 (tiny: 256 KB, L2-resident)
// ---------------------------------------------------------------------------
__global__ __launch_bounds__(256) void wconv_kernel(const float* __restrict__ W,
                                                    unsigned short* __restrict__ wt) {
    int n = blockIdx.x;
    int k = threadIdx.x;
    wt[n * 256 + k] = f2bf(W[k * 256 + n]);
}

// ---------------------------------------------------------------------------
// K4: MFMA bf16 GEMM  h16[M,256] = bf16(x)[M,256] @ Wt^T  + fused attn.
// 128x128 tile / block (2 heads per block -> A staged once for both),
// BK=64. A staged from fp32 x: float4 x2 load + 8 RNE cvt + ds_write_b128
// into the SAME XOR-chunk-swizzled layout (kills the conv prepass).
// B staged via global_load_lds w=16 from pre-converted wt.
// ---------------------------------------------------------------------------
__global__ __launch_bounds__(256) void gemm_kernel(const float* __restrict__ x,
                                                   const unsigned short* __restrict__ wt,
                                                   const float* __restrict__ att_src,
                                                   const float* __restrict__ att_dst,
                                                   unsigned short* __restrict__ h16,
                                                   float* __restrict__ a_src,
                                                   float* __restrict__ a_dst,
                                                   int M) {
    __shared__ unsigned short As[128 * 64];   // 16 KB
    __shared__ unsigned short Bs[128 * 64];   // 16 KB
    int tid = threadIdx.x;
    int w = tid >> 6, l = tid & 63;
    int quad = l >> 4, m16 = l & 15;
    int row0 = blockIdx.x * 128, col0 = blockIdx.y * 128;
    int hd0 = blockIdx.y * 2;                 // two heads per block

    f32x4 acc[2][8];
    #pragma unroll
    for (int t = 0; t < 2; ++t)
        #pragma unroll
        for (int u = 0; u < 8; ++u) acc[t][u] = (f32x4)(0.f);

    for (int k0 = 0; k0 < CH; k0 += 64) {
        // stage A from fp32: 1024 chunks of 8 elems, 4 per thread
        #pragma unroll
        for (int q = 0; q < 4; ++q) {
            int cslot = q * 256 + tid;
            int r = cslot >> 3, cs = cslot & 7;
            int j = cs ^ (r & 7);
            int grow = row0 + r; if (grow > M - 1) grow = M - 1;
            const float* gp = x + (size_t)grow * CH + k0 + j * 8;
            float4 v0 = *reinterpret_cast<const float4*>(gp);
            float4 v1 = *reinterpret_cast<const float4*>(gp + 4);
            short8 pk;
            pk[0] = (short)f2bf(v0.x); pk[1] = (short)f2bf(v0.y);
            pk[2] = (short)f2bf(v0.z); pk[3] = (short)f2bf(v0.w);
            pk[4] = (short)f2bf(v1.x); pk[5] = (short)f2bf(v1.y);
            pk[6] = (short)f2bf(v1.z); pk[7] = (short)f2bf(v1.w);
            *reinterpret_cast<short8*>(As + cslot * 8) = pk;
        }
        // stage B (bf16): 1024 chunks, 4 per thread, async DMA
        #pragma unroll
        for (int q = 0; q < 4; ++q) {
            int cslot = q * 256 + tid;
            int r = cslot >> 3, cs = cslot & 7;
            int j = cs ^ (r & 7);
            const unsigned short* gp = wt + (size_t)(col0 + r) * CH + k0 + j * 8;
            GLOAD_LDS16(gp, Bs + cslot * 8);
        }
        __syncthreads();
        #pragma unroll
        for (int ks = 0; ks < 2; ++ks) {
            short8 af[2], bf[8];
            int j = ks * 4 + quad;
            #pragma unroll
            for (int t = 0; t < 2; ++t) {
                int r = w * 32 + t * 16 + m16;
                int cs = j ^ (r & 7);
                af[t] = *reinterpret_cast<const short8*>(As + (r * 8 + cs) * 8);
            }
            #pragma unroll
            for (int u = 0; u < 8; ++u) {
                int c = u * 16 + m16;
                int cs = j ^ (c & 7);
                bf[u] = *reinterpret_cast<const short8*>(Bs + (c * 8 + cs) * 8);
            }
            #pragma unroll
            for (int t = 0; t < 2; ++t)
                #pragma unroll
                for (int u = 0; u < 8; ++u)
                    acc[t][u] = __builtin_amdgcn_mfma_f32_16x16x32_bf16(
                        af[t], bf[u], acc[t][u], 0, 0, 0);
        }
        __syncthreads();
    }

    // attn vectors: u 0..3 -> head hd0, u 4..7 -> head hd0+1
    float asr[8], adr[8];
    #pragma unroll
    for (int u = 0; u < 8; ++u) {
        int col = col0 + u * 16 + m16;
        asr[u] = att_src[col];
        adr[u] = att_dst[col];
    }

    // epilogue: C/D layout col=lane&15, row=quad*4+reg
    #pragma unroll
    for (int t = 0; t < 2; ++t) {
        #pragma unroll
        for (int reg = 0; reg < 4; ++reg) {
            int row = row0 + w * 32 + t * 16 + quad * 4 + reg;
            float sv0 = 0.f, dv0 = 0.f, sv1 = 0.f, dv1 = 0.f;
            #pragma unroll
            for (int u = 0; u < 4; ++u) {
                float c0 = acc[t][u][reg];
                float c1 = acc[t][u + 4][reg];
                sv0 += c0 * asr[u];     dv0 += c0 * adr[u];
                sv1 += c1 * asr[u + 4]; dv1 += c1 * adr[u + 4];
            }
            #pragma unroll
            for (int o = 8; o > 0; o >>= 1) {
                sv0 += __shfl_xor(sv0, o, 64);
                dv0 += __shfl_xor(dv0, o, 64);
                sv1 += __shfl_xor(sv1, o, 64);
                dv1 += __shfl_xor(dv1, o, 64);
            }
            if (row < M) {
                #pragma unroll
                for (int u = 0; u < 8; ++u) {
                    int col = col0 + u * 16 + m16;
                    h16[(size_t)row * CH + col] = f2bf(acc[t][u][reg]);
                }
                if (m16 == 0) {
                    a_src[row * HEADS + hd0]     = sv0;
                    a_dst[row * HEADS + hd0]     = dv0;
                    a_src[row * HEADS + hd0 + 1] = sv1;
                    a_dst[row * HEADS + hd0 + 1] = dv1;
                }
            }
        }
    }
}

// ---------------------------------------------------------------------------
// K6: aggregate — wave-per-node, ZERO LDS, ZERO barriers (unchanged, passed).
// ---------------------------------------------------------------------------
__global__ __launch_bounds__(256) void aggregate_kernel(const unsigned short* __restrict__ h16,
                                                        const float4* __restrict__ a_src4,
                                                        const float4* __restrict__ a_dst4,
                                                        const int* __restrict__ rowptr,
                                                        const int* __restrict__ srclist,
                                                        const float* __restrict__ bias,
                                                        float* __restrict__ out,
                                                        int N) {
    int tid = threadIdx.x;
    int w = tid >> 6, lane = tid & 63;
    int half = lane >> 5, l32 = lane & 31;
    int headC = l32 >> 3;
    int g = lane >> 2;
    int headS = lane & 3;
    int n = blockIdx.x * 4 + w;
    if (n >= N) return;

    int start = rowptr[n], end = rowptr[n + 1];
    float4 ad = a_dst4[n];
    float adS = headS == 0 ? ad.x : headS == 1 ? ad.y : headS == 2 ? ad.z : ad.w;

    float facc[8];
    #pragma unroll
    for (int j = 0; j < 8; ++j) facc[j] = 0.f;
    float denom = 0.f;

    for (int base = start; base < end; base += 16) {
        int cnt = min(end - base, 16);
        int sg = (g < cnt) ? srclist[base + g] : 0;
        float4 a = a_src4[sg];
        float av = headS == 0 ? a.x : headS == 1 ? a.y : headS == 2 ? a.z : a.w;
        float al = av + adS;
        al = (al >= 0.f) ? al : NEG_SLOPE * al;
        float ew = __expf(al);
        #pragma unroll
        for (int j = 0; j < 8; ++j) {
            int i = half * 8 + j;
            if (i < cnt) {
                int s   = __shfl(sg, i * 4, 64);
                float e = __shfl(ew, i * 4 + headC, 64);
                uint4 u = *((const uint4*)(h16 + (size_t)s * CH) + l32);
                denom += e;
                facc[0] += e * bflo(u.x);
                facc[1] += e * bfhi(u.x);
                facc[2] += e * bflo(u.y);
                facc[3] += e * bfhi(u.y);
                facc[4] += e * bflo(u.z);
                facc[5] += e * bfhi(u.z);
                facc[6] += e * bflo(u.w);
                facc[7] += e * bfhi(u.w);
            }
        }
    }

    #pragma unroll
    for (int j = 0; j < 8; ++j) facc[j] += __shfl_xor(facc[j], 32, 64);
    denom += __shfl_xor(denom, 32, 64);

    float inv = 1.f / (denom + 1e-16f);
    int cbase = l32 * 8 + half * 4;
    float4 b4 = *(const float4*)(bias + cbase);
    float4 o4;
    o4.x = (half ? facc[4] : facc[0]) * inv + b4.x;
    o4.y = (half ? facc[5] : facc[1]) * inv + b4.y;
    o4.z = (half ? facc[6] : facc[2]) * inv + b4.z;
    o4.w = (half ? facc[7] : facc[3]) * inv + b4.w;
    *(float4*)(out + (size_t)n * CH + cbase) = o4;
}

// ---------------------------------------------------------------------------
extern "C" void kernel_launch(void* const* d_in, const int* in_sizes, int n_in,
                              void* d_out, int out_size, void* d_ws, size_t ws_size,
                              hipStream_t stream) {
    const float* x       = (const float*)d_in[0];
    const int*   ei      = (const int*)d_in[1];
    const float* W       = (const float*)d_in[2];
    const float* att_src = (const float*)d_in[3];
    const float* att_dst = (const float*)d_in[4];
    const float* bias    = (const float*)d_in[5];
    float* out = (float*)d_out;

    int N = in_sizes[0] / CH;      // 50000
    int E = in_sizes[1] / 2;       // 800000
    int SB = (N + 255) / 256;      // scan blocks

    auto align = [](size_t v) { return (v + 255) & ~(size_t)255; };
    char* ws = (char*)d_ws;
    size_t off = 0;
    unsigned short* h16 = (unsigned short*)(ws + off); off = align(off + (size_t)N * CH * 2);
    unsigned short* wt  = (unsigned short*)(ws + off); off = align(off + (size_t)CH * CH * 2);
    float* a_src  = (float*)(ws + off); off = align(off + (size_t)N * HEADS * 4);
    float* a_dst  = (float*)(ws + off); off = align(off + (size_t)N * HEADS * 4);
    int*   rowptr = (int*)(ws + off);   off = align(off + (size_t)(N + 1) * 4);
    int*   cursor = (int*)(ws + off);   off = align(off + (size_t)N * 4);
    int*   bsum   = (int*)(ws + off);   off = align(off + (size_t)SB * 4);
    int*   boff   = (int*)(ws + off);   off = align(off + (size_t)SB * 4);
    int*   srclist= (int*)(ws + off);   off = align(off + (size_t)(E + N) * 4);

    // CSR build
    hipMemsetAsync(cursor, 0, (size_t)N * 4, stream);
    int E4 = E / 4;
    count_kernel<<<(E4 + 255) / 256, 256, 0, stream>>>((const int4*)(ei + E), cursor, N, E4);
    scan_p1<<<SB, 256, 0, stream>>>(cursor, bsum, N);
    scan_p2<<<1, 256, 0, stream>>>(bsum, boff, rowptr + N, SB);
    scan_p3<<<SB, 256, 0, stream>>>(cursor, boff, rowptr, cursor, N);
    scatter_kernel<<<(E4 + N + 255) / 256, 256, 0, stream>>>(ei, cursor, srclist, N, E);

    // dense phase: tiny W transpose, then MFMA GEMM (A converted in-kernel)
    wconv_kernel<<<256, 256, 0, stream>>>(W, wt);
    dim3 ggrid((N + 127) / 128, CH / 128);
    gemm_kernel<<<ggrid, 256, 0, stream>>>(x, wt, att_src, att_dst, h16, a_src, a_dst, N);

    // gather-aggregate
    aggregate_kernel<<<(N + 3) / 4, 256, 0, stream>>>(h16, (const float4*)a_src,
                                                      (const float4*)a_dst,
                                                      rowptr, srclist, bias, out, N);
}